// Round 9
// baseline (89.892 us; speedup 1.0000x reference)
//
#include <hip/hip_runtime.h>
#include <math.h>

#define N_TOK 8192
#define DIM   1024
#define NE    8
#define NR    16
#define NO    3072
#define OUT_ELEMS (N_TOK * NO)   // 25165824

__device__ __forceinline__ float softplusf(float z) {
  return z > 0.f ? z + log1pf(expf(-z)) : log1pf(expf(z));
}
__device__ __forceinline__ float ncdf(float z) {
  return 0.5f * erfcf(-z * 0.70710678118654752f);
}

#define FMA4(A, S, W) { (A).x = fmaf((S),(W).x,(A).x); (A).y = fmaf((S),(W).y,(A).y); \
                        (A).z = fmaf((S),(W).z,(A).z); (A).w = fmaf((S),(W).w,(A).w); }
#define Z4 make_float4(0.f,0.f,0.f,0.f)

// ---------------------------------------------------------------------------
// kA2: gating GEMM. 128 blocks x 64 tokens x 16 outs (8 gate + 8 noise), K=1024.
// 16 chunks of 64 k. Reg-staged (global->reg->LDS), next-chunk prefetch
// overlaps compute. x in LDS [64][65] (lane=token b32 read => 2-way, free).
// w in LDS [64][20], read wave-uniform (broadcast). acc register-resident:
// thread (tok=t&63, og=t>>6) owns 1 token x 4 outs. No cross-lane reduction.
// Epilogue on wave 0: softplus/top-2/ncdf/ballot + per-block partials.
// ---------------------------------------------------------------------------
__global__ __launch_bounds__(256) void kA2(const float* __restrict__ x,
    const float* __restrict__ wg, const float* __restrict__ wn,
    const float* __restrict__ nz, int* __restrict__ eid, float* __restrict__ part) {
  __shared__ float xl[64 * 65];
  __shared__ float wl[64 * 20];
  __shared__ float lgS[64 * 20];
  int t = threadIdx.x;
  int n0 = blockIdx.x << 6;
  int tok = t & 63, og = t >> 6;
  // x staging slots: 4 per thread; slot s = i*256+t -> row s>>4, col-quad s&15
  int tk0 = t >> 4,           j0 = t & 15;
  int tk1 = (t + 256) >> 4,   j1 = t & 15;
  int tk2 = (t + 512) >> 4,   j2 = t & 15;
  int tk3 = (t + 768) >> 4,   j3 = t & 15;
  const float* xp0 = x + (size_t)(n0 + tk0) * DIM + (j0 << 2);
  const float* xp1 = x + (size_t)(n0 + tk1) * DIM + (j1 << 2);
  const float* xp2 = x + (size_t)(n0 + tk2) * DIM + (j2 << 2);
  const float* xp3 = x + (size_t)(n0 + tk3) * DIM + (j3 << 2);
  // w staging: thread -> k=t>>2 (0..63), oq=t&3 (0,1: gate lo/hi; 2,3: noise)
  int wk = t >> 2, oq = t & 3;
  const float* wp = (oq < 2) ? (wg + (size_t)wk * NE + (oq << 2))
                             : (wn + (size_t)wk * NE + ((oq - 2) << 2));
  float4 acc = Z4;
  float4 xa0 = *(const float4*)xp0;
  float4 xa1 = *(const float4*)xp1;
  float4 xa2 = *(const float4*)xp2;
  float4 xa3 = *(const float4*)xp3;
  float4 wa  = *(const float4*)wp;
  for (int c = 0; c < 16; ++c) {
    __syncthreads();                      // previous compute done reading LDS
    xl[tk0 * 65 + (j0 << 2) + 0] = xa0.x; xl[tk0 * 65 + (j0 << 2) + 1] = xa0.y;
    xl[tk0 * 65 + (j0 << 2) + 2] = xa0.z; xl[tk0 * 65 + (j0 << 2) + 3] = xa0.w;
    xl[tk1 * 65 + (j1 << 2) + 0] = xa1.x; xl[tk1 * 65 + (j1 << 2) + 1] = xa1.y;
    xl[tk1 * 65 + (j1 << 2) + 2] = xa1.z; xl[tk1 * 65 + (j1 << 2) + 3] = xa1.w;
    xl[tk2 * 65 + (j2 << 2) + 0] = xa2.x; xl[tk2 * 65 + (j2 << 2) + 1] = xa2.y;
    xl[tk2 * 65 + (j2 << 2) + 2] = xa2.z; xl[tk2 * 65 + (j2 << 2) + 3] = xa2.w;
    xl[tk3 * 65 + (j3 << 2) + 0] = xa3.x; xl[tk3 * 65 + (j3 << 2) + 1] = xa3.y;
    xl[tk3 * 65 + (j3 << 2) + 2] = xa3.z; xl[tk3 * 65 + (j3 << 2) + 3] = xa3.w;
    *(float4*)&wl[wk * 20 + (oq << 2)] = wa;
    __syncthreads();
    if (c < 15) {                         // prefetch next chunk (in flight during compute)
      int ko = (c + 1) << 6;
      xa0 = *(const float4*)(xp0 + ko);
      xa1 = *(const float4*)(xp1 + ko);
      xa2 = *(const float4*)(xp2 + ko);
      xa3 = *(const float4*)(xp3 + ko);
      wa  = *(const float4*)(wp + (size_t)ko * NE);
    }
    const float* xr = &xl[tok * 65];
    const float* wr = &wl[og << 2];
    #pragma unroll
    for (int kq = 0; kq < 16; ++kq) {
      float xv0 = xr[(kq << 2) + 0];
      float xv1 = xr[(kq << 2) + 1];
      float xv2 = xr[(kq << 2) + 2];
      float xv3 = xr[(kq << 2) + 3];
      float4 w0 = *(const float4*)&wr[((kq << 2) + 0) * 20];
      float4 w1 = *(const float4*)&wr[((kq << 2) + 1) * 20];
      float4 w2 = *(const float4*)&wr[((kq << 2) + 2) * 20];
      float4 w3 = *(const float4*)&wr[((kq << 2) + 3) * 20];
      FMA4(acc, xv0, w0);
      FMA4(acc, xv1, w1);
      FMA4(acc, xv2, w2);
      FMA4(acc, xv3, w3);
    }
  }
  *(float4*)&lgS[tok * 20 + (og << 2)] = acc;   // og 0,1: gate 0-7; 2,3: noise 8-15
  __syncthreads();
  if (t < 64) {
    int n = n0 + t;
    float cl[8], st[8], lg[8];
    float4 nzv0 = *(const float4*)(nz + (size_t)n * NE);
    float4 nzv1 = *(const float4*)(nz + (size_t)n * NE + 4);
    float nzv[8] = {nzv0.x, nzv0.y, nzv0.z, nzv0.w, nzv1.x, nzv1.y, nzv1.z, nzv1.w};
    #pragma unroll
    for (int e = 0; e < 8; ++e) cl[e] = lgS[t * 20 + e];
    #pragma unroll
    for (int e = 0; e < 8; ++e) {
      st[e] = softplusf(lgS[t * 20 + 8 + e]) + 0.01f;
      lg[e] = fmaf(nzv[e], st[e], cl[e]);
    }
    float m1 = -1e30f, m2 = -1e30f; int idx = 0;
    #pragma unroll
    for (int e = 0; e < 8; ++e) {
      float v = lg[e];
      if (v > m1)      { m2 = m1; m1 = v; idx = e; }
      else if (v > m2) { m2 = v; }
    }
    eid[n] = idx;
    float pr[8], cw[8];
    #pragma unroll
    for (int e = 0; e < 8; ++e) {
      float thr = (lg[e] > m2) ? m2 : m1;
      pr[e] = ncdf((cl[e] - thr) / st[e]);
    }
    #pragma unroll
    for (int e = 0; e < 8; ++e) cw[e] = (float)__popcll(__ballot(idx == e));
    #pragma unroll
    for (int e = 0; e < 8; ++e) {
      #pragma unroll
      for (int off = 1; off <= 32; off <<= 1) pr[e] += __shfl_xor(pr[e], off);
    }
    if (t == 0) {
      #pragma unroll
      for (int e = 0; e < 8; ++e) {
        part[blockIdx.x * 16 + e]     = cw[e];
        part[blockIdx.x * 16 + 8 + e] = pr[e];
      }
    }
  }
}

// ---------------------------------------------------------------------------
// kC: fused counts reduction (128x16 partials) + bucket scatter. 32 blocks.
// ---------------------------------------------------------------------------
__global__ __launch_bounds__(256) void kC(const float* __restrict__ part,
    const int* __restrict__ eid, int* __restrict__ fill, int* __restrict__ bucket,
    float* __restrict__ outIL, int* __restrict__ counts) {
  __shared__ float red[16][16];
  __shared__ int cnt_s[8], lcnt[8], lbase[8];
  int t = threadIdx.x;
  int s = t & 15, g = t >> 4;
  float sum = 0.f;
  #pragma unroll
  for (int j = 0; j < 8; ++j) sum += part[(g + 16 * j) * 16 + s];
  red[g][s] = sum;
  if (t < 8) lcnt[t] = 0;
  __syncthreads();
  if (t < 16) {
    float tot = 0.f;
    #pragma unroll
    for (int gg = 0; gg < 16; ++gg) tot += red[gg][t];
    if (blockIdx.x == 0) outIL[t] = tot;
    if (t < 8) {
      cnt_s[t] = (int)(tot + 0.5f);
      if (blockIdx.x == 0) counts[t] = (int)(tot + 0.5f);
    }
  }
  __syncthreads();
  int n = blockIdx.x * 256 + t;
  int e = eid[n];
  int rank = atomicAdd(&lcnt[e], 1);
  __syncthreads();
  if (t < 8) lbase[t] = atomicAdd(&fill[t], lcnt[t]);
  __syncthreads();
  int off = 0;
  #pragma unroll
  for (int i = 0; i < 8; ++i) if (i < e) off += cnt_s[i];
  bucket[off + lbase[e] + rank] = n;
}

// ---------------------------------------------------------------------------
// kD2: h_sorted = lora_a[e] @ x[bucket], kE/kA2-shaped GEMM. 135 tiles of
// 64 sorted tokens x 16 r, K=1024 in 16 chunks. Same staging/banks as kA2;
// w chunk transposed from la[e][r][d] during LDS write. h written directly.
// ---------------------------------------------------------------------------
__global__ __launch_bounds__(256) void kD2(const float* __restrict__ x,
    const float* __restrict__ la, const int* __restrict__ counts,
    const int* __restrict__ bucket, float* __restrict__ h) {
  __shared__ float xl[64 * 65];
  __shared__ float wl[64 * 20];
  __shared__ int toks[64];
  int tile = blockIdx.x;
  int e = -1, jt = 0, off = 0;
  { int tot = 0, o = 0;
    #pragma unroll
    for (int i = 0; i < 8; ++i) {
      int c = counts[i]; int nt = (c + 63) >> 6;
      if (e < 0 && tile < tot + nt) { e = i; jt = tile - tot; off = o; }
      tot += nt; o += c;
    } }
  if (e < 0) return;
  int cnt = counts[e];
  int p0 = off + (jt << 6);
  int valid = min(64, cnt - (jt << 6));
  int t = threadIdx.x;
  if (t < 64) toks[t] = bucket[p0 + min(t, valid - 1)];
  __syncthreads();
  int tok = t & 63, og = t >> 6;
  int tk0 = t >> 4,         j0 = t & 15;
  int tk1 = (t + 256) >> 4;
  int tk2 = (t + 512) >> 4;
  int tk3 = (t + 768) >> 4;
  const float* xp0 = x + (size_t)toks[tk0] * DIM + (j0 << 2);
  const float* xp1 = x + (size_t)toks[tk1] * DIM + (j0 << 2);
  const float* xp2 = x + (size_t)toks[tk2] * DIM + (j0 << 2);
  const float* xp3 = x + (size_t)toks[tk3] * DIM + (j0 << 2);
  // w staging: thread -> r=t>>4 (0..15), kq=t&15 (4-float chunk along k)
  int wr_ = t >> 4, wkq = t & 15;
  const float* wp = la + (size_t)e * (NR * DIM) + (size_t)wr_ * DIM + (wkq << 2);
  float4 acc = Z4;
  float4 xa0 = *(const float4*)xp0;
  float4 xa1 = *(const float4*)xp1;
  float4 xa2 = *(const float4*)xp2;
  float4 xa3 = *(const float4*)xp3;
  float4 wa  = *(const float4*)wp;
  for (int c = 0; c < 16; ++c) {
    __syncthreads();
    xl[tk0 * 65 + (j0 << 2) + 0] = xa0.x; xl[tk0 * 65 + (j0 << 2) + 1] = xa0.y;
    xl[tk0 * 65 + (j0 << 2) + 2] = xa0.z; xl[tk0 * 65 + (j0 << 2) + 3] = xa0.w;
    xl[tk1 * 65 + (j0 << 2) + 0] = xa1.x; xl[tk1 * 65 + (j0 << 2) + 1] = xa1.y;
    xl[tk1 * 65 + (j0 << 2) + 2] = xa1.z; xl[tk1 * 65 + (j0 << 2) + 3] = xa1.w;
    xl[tk2 * 65 + (j0 << 2) + 0] = xa2.x; xl[tk2 * 65 + (j0 << 2) + 1] = xa2.y;
    xl[tk2 * 65 + (j0 << 2) + 2] = xa2.z; xl[tk2 * 65 + (j0 << 2) + 3] = xa2.w;
    xl[tk3 * 65 + (j0 << 2) + 0] = xa3.x; xl[tk3 * 65 + (j0 << 2) + 1] = xa3.y;
    xl[tk3 * 65 + (j0 << 2) + 2] = xa3.z; xl[tk3 * 65 + (j0 << 2) + 3] = xa3.w;
    // transpose-write w: wl[k][r], k = 4*wkq+m
    wl[((wkq << 2) + 0) * 20 + wr_] = wa.x;
    wl[((wkq << 2) + 1) * 20 + wr_] = wa.y;
    wl[((wkq << 2) + 2) * 20 + wr_] = wa.z;
    wl[((wkq << 2) + 3) * 20 + wr_] = wa.w;
    __syncthreads();
    if (c < 15) {
      int ko = (c + 1) << 6;
      xa0 = *(const float4*)(xp0 + ko);
      xa1 = *(const float4*)(xp1 + ko);
      xa2 = *(const float4*)(xp2 + ko);
      xa3 = *(const float4*)(xp3 + ko);
      wa  = *(const float4*)(wp + ko);
    }
    const float* xr = &xl[tok * 65];
    const float* wrp = &wl[og << 2];
    #pragma unroll
    for (int kq = 0; kq < 16; ++kq) {
      float xv0 = xr[(kq << 2) + 0];
      float xv1 = xr[(kq << 2) + 1];
      float xv2 = xr[(kq << 2) + 2];
      float xv3 = xr[(kq << 2) + 3];
      float4 w0 = *(const float4*)&wrp[((kq << 2) + 0) * 20];
      float4 w1 = *(const float4*)&wrp[((kq << 2) + 1) * 20];
      float4 w2 = *(const float4*)&wrp[((kq << 2) + 2) * 20];
      float4 w3 = *(const float4*)&wrp[((kq << 2) + 3) * 20];
      FMA4(acc, xv0, w0);
      FMA4(acc, xv1, w1);
      FMA4(acc, xv2, w2);
      FMA4(acc, xv3, w3);
    }
  }
  if (tok < valid)
    *(float4*)(h + (size_t)(p0 + tok) * NR + (og << 2)) = acc;
}

// ---------------------------------------------------------------------------
// kE: out[n] = lora_b[e] @ h_sorted. Tiles: 64 tokens x 256 outs. (unchanged)
// ---------------------------------------------------------------------------
__global__ __launch_bounds__(256) void kE(const float* __restrict__ h,
    const float* __restrict__ lb, const int* __restrict__ counts,
    const int* __restrict__ bucket, float* __restrict__ out) {
  __shared__ float bt[16][260];
  __shared__ float ht[16][64];
  __shared__ int toks[64];
  int tile = blockIdx.y;
  int e = -1, jt = 0, off = 0;
  { int tot = 0, o = 0;
    #pragma unroll
    for (int i = 0; i < 8; ++i) {
      int c = counts[i]; int nt = (c + 63) >> 6;
      if (e < 0 && tile < tot + nt) { e = i; jt = tile - tot; off = o; }
      tot += nt; o += c;
    } }
  if (e < 0) return;
  int cnt = counts[e];
  int p0 = off + (jt << 6);
  int valid = min(64, cnt - (jt << 6));
  int o0 = blockIdx.x << 8;
  int t = threadIdx.x;
  if (t < 64) toks[t] = bucket[p0 + min(t, valid - 1)];
  const float* bbase = lb + ((size_t)e * NO + o0) * NR;
  #pragma unroll
  for (int kk = 0; kk < 4; ++kk) {
    int idx = (kk << 8) + t;
    int o = idx >> 2, rq = (idx & 3) << 2;
    float4 v = *(const float4*)(bbase + o * NR + rq);
    bt[rq + 0][o] = v.x; bt[rq + 1][o] = v.y; bt[rq + 2][o] = v.z; bt[rq + 3][o] = v.w;
  }
  { int tok = t >> 2, rq = (t & 3) << 2;
    float4 v = *(const float4*)(h + (size_t)(p0 + min(tok, valid - 1)) * NR + rq);
    ht[rq + 0][tok] = v.x; ht[rq + 1][tok] = v.y; ht[rq + 2][tok] = v.z; ht[rq + 3][tok] = v.w; }
  __syncthreads();
  int og = t & 31, tokg = t >> 5;
  int ob = og << 2, tb = tokg << 3;
  float4 z = Z4;
  float4 aL0=z,aL1=z,aL2=z,aL3=z,aL4=z,aL5=z,aL6=z,aL7=z;
  float4 aH0=z,aH1=z,aH2=z,aH3=z,aH4=z,aH5=z,aH6=z,aH7=z;
  #pragma unroll
  for (int r = 0; r < 16; ++r) {
    float4 blo = *(const float4*)&bt[r][ob];
    float4 bhi = *(const float4*)&bt[r][ob + 128];
    float4 h0  = *(const float4*)&ht[r][tb];
    float4 h1  = *(const float4*)&ht[r][tb + 4];
    FMA4(aL0, h0.x, blo); FMA4(aH0, h0.x, bhi);
    FMA4(aL1, h0.y, blo); FMA4(aH1, h0.y, bhi);
    FMA4(aL2, h0.z, blo); FMA4(aH2, h0.z, bhi);
    FMA4(aL3, h0.w, blo); FMA4(aH3, h0.w, bhi);
    FMA4(aL4, h1.x, blo); FMA4(aH4, h1.x, bhi);
    FMA4(aL5, h1.y, blo); FMA4(aH5, h1.y, bhi);
    FMA4(aL6, h1.z, blo); FMA4(aH6, h1.z, bhi);
    FMA4(aL7, h1.w, blo); FMA4(aH7, h1.w, bhi);
  }
  #define ST(J, AL, AH) { int tt = tb + (J); if (tt < valid) { \
      float* p = out + (size_t)toks[tt] * NO + o0 + ob; \
      *(float4*)p = AL; *(float4*)(p + 128) = AH; } }
  ST(0, aL0, aH0); ST(1, aL1, aH1); ST(2, aL2, aH2); ST(3, aL3, aH3);
  ST(4, aL4, aH4); ST(5, aL5, aH5); ST(6, aL6, aH6); ST(7, aL7, aH7);
  #undef ST
}

// ---------------------------------------------------------------------------
extern "C" void kernel_launch(void* const* d_in, const int* in_sizes, int n_in,
                              void* d_out, int out_size, void* d_ws, size_t ws_size,
                              hipStream_t stream) {
  const float* x  = (const float*)d_in[0];
  const float* wg = (const float*)d_in[1];
  const float* wn = (const float*)d_in[2];
  const float* la = (const float*)d_in[3];
  const float* lb = (const float*)d_in[4];
  const float* nz = (const float*)d_in[5];
  float* out = (float*)d_out;

  char* ws = (char*)d_ws;
  float* h        = (float*)(ws);                 // 524288 B
  int*   eid      = (int*)  (ws + 524288);        // 32768 B
  int*   bucket   = (int*)  (ws + 557056);        // 32768 B
  float* partials = (float*)(ws + 589824);        // 8192 B (128*16*4)
  int*   counts   = (int*)  (ws + 622592);        // 32 B
  int*   fill     = (int*)  (ws + 622624);        // 32 B

  hipMemsetAsync(fill, 0, 32, stream);
  kA2<<<128, 256, 0, stream>>>(x, wg, wn, nz, eid, partials);
  kC<<<32, 256, 0, stream>>>(partials, eid, fill, bucket, out + OUT_ELEMS, counts);
  kD2<<<135, 256, 0, stream>>>(x, la, counts, bucket, h);
  kE<<<dim3(12, 135), 256, 0, stream>>>(h, lb, counts, bucket, out);
}